// Round 7
// baseline (127.458 us; speedup 1.0000x reference)
//
#include <hip/hip_runtime.h>
#include <stdint.h>

#define NB 4
#define NC 17
#define HH 8
#define SS 512
#define DD 64
#define CT 64   // columns per block tile

typedef __attribute__((ext_vector_type(8))) short bf16x8;
typedef __attribute__((ext_vector_type(4))) float f32x4;

// ws layout (bytes):
//   W1mbf : [17][8][64][64] bf16 = 1,114,112
#define WS_W1   0

__device__ __forceinline__ unsigned short f2bf(float f) {
  unsigned int x; __builtin_memcpy(&x, &f, 4);
  return (unsigned short)((x + 0x7fff + ((x >> 16) & 1)) >> 16);
}
__device__ __forceinline__ bf16x8 cvt8(float4 a, float4 b) {
  union { bf16x8 v; unsigned short u[8]; } t;
  t.u[0] = f2bf(a.x); t.u[1] = f2bf(a.y); t.u[2] = f2bf(a.z); t.u[3] = f2bf(a.w);
  t.u[4] = f2bf(b.x); t.u[5] = f2bf(b.y); t.u[6] = f2bf(b.z); t.u[7] = f2bf(b.w);
  return t.v;
}

// ---- K0: W1mbf[c][h][.] = sum_B W1[B][h][.] * softmax(alpha, axis=B)[c,B,h] ----
__global__ __launch_bounds__(256) void k_prep(const float* __restrict__ W1,
                                              const float* __restrict__ alpha,
                                              unsigned short* __restrict__ W1mbf) {
  int tid = threadIdx.x;
  int cb = blockIdx.x;
  int c = cb >> 3, hh = cb & 7;
  __shared__ float sm[NB];
  if (tid == 0) {
    float a[NB], mx = -1e30f;
    for (int B = 0; B < NB; B++) { a[B] = alpha[(c * NB + B) * HH + hh]; mx = fmaxf(mx, a[B]); }
    float s = 0.f;
    for (int B = 0; B < NB; B++) { a[B] = __expf(a[B] - mx); s += a[B]; }
    for (int B = 0; B < NB; B++) sm[B] = a[B] / s;
  }
  __syncthreads();
  float s0 = sm[0], s1 = sm[1], s2 = sm[2], s3 = sm[3];
  for (int idx = tid; idx < DD * DD; idx += blockDim.x) {
    float v = W1[((0 * HH + hh) * DD * DD) + idx] * s0 +
              W1[((1 * HH + hh) * DD * DD) + idx] * s1 +
              W1[((2 * HH + hh) * DD * DD) + idx] * s2 +
              W1[((3 * HH + hh) * DD * DD) + idx] * s3;
    W1mbf[((size_t)(c * HH + hh)) * DD * DD + idx] = f2bf(v);
  }
}

// ---- Fused: block = (bh, 64-col tile).
// Phase 1: build T[5][64][m] in LDS (class-uniform 16-col MFMA tiles via local
//          bj grouping; bj=0 columns broadcast to all planes).
// Phase 2: natural-order rows; per 16-row tile compute q.T[B] for ALL 5 planes,
//          then per-row select acc[bseq[row]]. No gathers, no scatters.
__global__ __launch_bounds__(256, 4) void k_fused(const float* __restrict__ query,
                                                  const float* __restrict__ key,
                                                  const int* __restrict__ bseq,
                                                  const unsigned short* __restrict__ W1mbf,
                                                  float* __restrict__ out) {
  int bx = blockIdx.x;
  int bh = bx & 63, jt = bx >> 6;   // same-bh blocks 64 apart -> same XCD
  int b = bh >> 3, h = bh & 7;
  int j0 = jt * CT;
  int tid = threadIdx.x, wave = tid >> 6, lane = tid & 63;
  int quad = lane >> 4, l16 = lane & 15;

  __shared__ __align__(16) unsigned short Tl[5][CT][72];  // 46,080 B
  __shared__ int ord[CT], lgs[6], cnt[5], cur[5];
  __shared__ int p1list[44], n1s[5], n1b[5], n1tot;
  __shared__ int sb[SS];  // row buckets, natural order

  // stage row buckets (coalesced, 2 KB)
  for (int i = tid; i < SS; i += 256) sb[i] = bseq[b * SS + i];

  // ---- local column grouping by bj ----
  if (tid < 5) cnt[tid] = 0;
  __syncthreads();
  int mybj = 0;
  if (tid < CT) { mybj = sb[j0 + tid]; atomicAdd(&cnt[mybj], 1); }
  __syncthreads();
  if (tid == 0) {
    lgs[0] = 0;
    for (int a = 0; a < 5; a++) lgs[a + 1] = lgs[a] + cnt[a];
  }
  __syncthreads();
  if (tid < 5) cur[tid] = lgs[tid];
  __syncthreads();
  if (tid < CT) ord[atomicAdd(&cur[mybj], 1)] = tid;
  if (tid < 5) n1s[tid] = ((lgs[tid + 1] - lgs[tid] + 15) >> 4) * ((tid == 0) ? 1 : 5);
  __syncthreads();
  if (tid == 0) {
    int a0 = 0;
    for (int a = 0; a < 5; a++) { n1b[a] = a0; a0 += n1s[a]; }
    n1tot = a0;
  }
  __syncthreads();
  if (tid < 5) {
    int a = tid;
    int ls = lgs[a], le = lgs[a + 1];
    int w = n1b[a];
    for (int t0 = ls; t0 < le; t0 += 16) {
      if (a == 0) {
        p1list[w++] = t0 | (le << 6) | (1 << 21);  // c=0, bcast all planes
      } else {
        for (int B = 0; B < 5; B++) {
          int c = (B == 0) ? 0 : (B - 1) * NB + a;
          p1list[w++] = t0 | (le << 6) | (c << 13) | (B << 18);
        }
      }
    }
  }
  __syncthreads();

  // ---- phase 1: Tl[B][col][m] = sum_n key[col][n] * W_c(B,bj)[m][n] ----
  for (int idx = wave; idx < n1tot; idx += 4) {
    int e = p1list[idx];
    int t0 = e & 63, le = (e >> 6) & 127, c = (e >> 13) & 31, B = (e >> 18) & 7;
    int bc = (e >> 21) & 1;
    const unsigned short* Wc = W1mbf + ((size_t)(c * HH + h) << 12);
    int p = t0 + l16; if (p > le - 1) p = le - 1;
    int cl = ord[p];
    const float* kp = &key[((size_t)(bh * SS + j0 + cl)) * DD + quad * 8];
    float4 ka = *(const float4*)kp, kb = *(const float4*)(kp + 4);
    float4 kc = *(const float4*)(kp + 32), kd = *(const float4*)(kp + 36);
    bf16x8 af0 = cvt8(ka, kb);
    bf16x8 af1 = cvt8(kc, kd);
    int cr[4];
#pragma unroll
    for (int reg = 0; reg < 4; reg++) {
      int pr = t0 + quad * 4 + reg;
      cr[reg] = (pr < le) ? ord[pr] : -1;
    }
#pragma unroll
    for (int nt = 0; nt < 4; nt++) {
      const unsigned short* wp = &Wc[(nt * 16 + l16) * DD + quad * 8];
      bf16x8 b0 = *(const bf16x8*)wp;
      bf16x8 b1 = *(const bf16x8*)(wp + 32);
      f32x4 acc = {0.f, 0.f, 0.f, 0.f};
      acc = __builtin_amdgcn_mfma_f32_16x16x32_bf16(af0, b0, acc, 0, 0, 0);
      acc = __builtin_amdgcn_mfma_f32_16x16x32_bf16(af1, b1, acc, 0, 0, 0);
#pragma unroll
      for (int reg = 0; reg < 4; reg++) {
        if (cr[reg] >= 0) {
          unsigned short v = f2bf(acc[reg]);
          if (bc) {
#pragma unroll
            for (int Bw = 0; Bw < 5; Bw++) Tl[Bw][cr[reg]][nt * 16 + l16] = v;
          } else {
            Tl[B][cr[reg]][nt * 16 + l16] = v;
          }
        }
      }
    }
  }
  __syncthreads();

  // ---- phase 2: natural-order row tiles, 5-plane MFMA + per-row select ----
  for (int rt = wave; rt < SS / 16; rt += 4) {
    int p0 = rt * 16;
    const float* qp = &query[((size_t)(bh * SS + p0 + l16)) * DD + quad * 8];
    float4 a0 = *(const float4*)qp, a1 = *(const float4*)(qp + 4);
    float4 a2 = *(const float4*)(qp + 32), a3 = *(const float4*)(qp + 36);
    bf16x8 af0 = cvt8(a0, a1);
    bf16x8 af1 = cvt8(a2, a3);
    int Bq[4];
#pragma unroll
    for (int reg = 0; reg < 4; reg++) Bq[reg] = sb[p0 + quad * 4 + reg];
#pragma unroll
    for (int ct = 0; ct < CT / 16; ct++) {
      f32x4 acc[5];
#pragma unroll
      for (int P = 0; P < 5; P++) {
        const unsigned short* tp = &Tl[P][ct * 16 + l16][quad * 8];
        bf16x8 tb0 = *(const bf16x8*)tp;
        bf16x8 tb1 = *(const bf16x8*)(tp + 32);
        f32x4 z = {0.f, 0.f, 0.f, 0.f};
        z = __builtin_amdgcn_mfma_f32_16x16x32_bf16(af0, tb0, z, 0, 0, 0);
        z = __builtin_amdgcn_mfma_f32_16x16x32_bf16(af1, tb1, z, 0, 0, 0);
        acc[P] = z;
      }
#pragma unroll
      for (int reg = 0; reg < 4; reg++) {
        int Bv = Bq[reg];
        float v = acc[0][reg];
        v = (Bv == 1) ? acc[1][reg] : v;
        v = (Bv == 2) ? acc[2][reg] : v;
        v = (Bv == 3) ? acc[3][reg] : v;
        v = (Bv == 4) ? acc[4][reg] : v;
        out[((size_t)(bh * SS + p0 + quad * 4 + reg)) * SS + j0 + ct * 16 + l16] = v;
      }
    }
  }
}

extern "C" void kernel_launch(void* const* d_in, const int* in_sizes, int n_in,
                              void* d_out, int out_size, void* d_ws, size_t ws_size,
                              hipStream_t stream) {
  const float* q = (const float*)d_in[0];
  const float* k = (const float*)d_in[1];
  const int* bseq = (const int*)d_in[2];
  const float* W1 = (const float*)d_in[3];
  const float* alpha = (const float*)d_in[4];
  float* out = (float*)d_out;
  char* ws = (char*)d_ws;
  unsigned short* W1mbf = (unsigned short*)(ws + WS_W1);

  hipLaunchKernelGGL(k_prep, dim3(NC * HH), dim3(256), 0, stream, W1, alpha, W1mbf);
  hipLaunchKernelGGL(k_fused, dim3(64 * (SS / CT)), dim3(256), 0, stream,
                     q, k, bseq, W1mbf, out);
}